// Round 1
// baseline (468.311 us; speedup 1.0000x reference)
//
#include <hip/hip_runtime.h>
#include <cstddef>
#include <cstdint>

// ---------------------------------------------------------------------------
// attention_net_noc: pointer-network decode step.
// 1M jobs + 0.5M machines -> 16-d tanh MLP embeddings; two additive-attention
// glimpses; masked argmax over job logits; argmax over machine logits; logpas.
// fp32 throughout (argmax must match numpy fp32 reference; no fp32 MFMA on
// CDNA4 anyway -> vector ALU).
// ---------------------------------------------------------------------------

constexpr int NJ = 1000000;
constexpr int NM = 500000;
constexpr float NEGV = -1e8f;

constexpr int BLK = 256;
constexpr int GB_J = 680;              // job-partition blocks in split kernels
constexpr int GB_M = 344;              // machine-partition blocks
constexpr int GB_TOT = GB_J + GB_M;    // 1024
constexpr int GB_JL = 1024;            // job-logits grid
constexpr int GB_ML = 512;             // machine-logits grid

// ---- workspace layout (float offsets from start of d_ws) ----
constexpr int S_QKJA = 0;    // 16: ja_Wq@g1 + ja_bq
constexpr int S_QK2J = 16;   // 16: aj_Wq@e_js + aj_bq
constexpr int S_QK2M = 32;   // 16: am_Wq@e_js + am_bq
constexpr int S_EJS  = 48;   // 16: E_j[sel_j]
constexpr int S_QKMA = 64;   // 16: ma_Wq@g2 + ma_bq
constexpr int S_LOGPJ = 80;
constexpr int S_SELJ  = 81;  // stored as float (exact, < 2^24)
constexpr int P1J = 96;                    // 680*17 glimpse1 jobs partials (l, s[16])
constexpr int P1M = P1J + GB_J * 17;       // 344*17
constexpr int P2V = P1M + GB_M * 17;       // 1024 argmax vals
constexpr int P2I = P2V + GB_JL;           // 1024 argmax idx (as float)
constexpr int P2L = P2I + GB_JL;           // 1024 sum-exp
constexpr int P3J = P2L + GB_JL;           // 680*17 glimpse2 jobs
constexpr int P3M = P3J + GB_J * 17;       // 344*17
constexpr int P4V = P3M + GB_M * 17;       // 512
constexpr int P4I = P4V + GB_ML;
constexpr int P4L = P4I + GB_ML;
constexpr size_t E_OFF = 65536;            // float offset of E_j cache (256KB in)

struct Params {
    const float *jobs, *machines;
    const int *mask;
    const float *jW1, *jb1, *jW2, *jb2;
    const float *mW1, *mb1, *mW2, *mb2;
    const float *aj_Wq, *aj_bq, *aj_Wr, *aj_V;
    const float *am_Wq, *am_bq, *am_Wr, *am_V;
    const float *ja_Wq, *ja_bq, *ja_Wr, *ja_V;
    const float *ma_Wq, *ma_bq, *ma_Wr, *ma_V;
    const float *g1W, *g1b, *g2W, *g2b, *last_j;
    float *S;        // smalls + partials (in ws)
    float *Ej, *Em;  // embedding cache (in ws; valid only if CACHE)
    float *out;
};

// ---------------------------------------------------------------------------
// device helpers
// ---------------------------------------------------------------------------

// tanh(x) = 1 - 2/(e^{2x}+1). |x| <= ~3 here; abs err ~2e-7 vs np.tanh.
// Robust at e->inf (returns 1) and e->0 (returns -1).
__device__ __forceinline__ float fast_tanh(float x) {
    float e = __expf(2.0f * x);
    return 1.0f - __fdividef(2.0f, e + 1.0f);
}

__device__ __forceinline__ void load16(const float* __restrict__ X, size_t r, float (&x)[16]) {
    const float4* p4 = reinterpret_cast<const float4*>(X) + r * 4;
    float4 a = p4[0], b = p4[1], c = p4[2], d = p4[3];
    x[0]=a.x; x[1]=a.y; x[2]=a.z; x[3]=a.w;
    x[4]=b.x; x[5]=b.y; x[6]=b.z; x[7]=b.w;
    x[8]=c.x; x[9]=c.y; x[10]=c.z; x[11]=c.w;
    x[12]=d.x; x[13]=d.y; x[14]=d.z; x[15]=d.w;
}

__device__ __forceinline__ void store16(float* __restrict__ X, size_t r, const float (&x)[16]) {
    float4* p4 = reinterpret_cast<float4*>(X) + r * 4;
    p4[0] = make_float4(x[0], x[1], x[2], x[3]);
    p4[1] = make_float4(x[4], x[5], x[6], x[7]);
    p4[2] = make_float4(x[8], x[9], x[10], x[11]);
    p4[3] = make_float4(x[12], x[13], x[14], x[15]);
}

// e = tanh(W2 @ tanh(W1 @ x + b1) + b2)   (torch Linear: y_i = sum_k W[i,k] x_k + b_i)
__device__ __forceinline__ void emb16(const float (&x)[16],
                                      const float* __restrict__ W1, const float* __restrict__ b1,
                                      const float* __restrict__ W2, const float* __restrict__ b2,
                                      float (&e)[16]) {
    float h[16];
#pragma unroll
    for (int i = 0; i < 16; ++i) {
        float a = b1[i];
#pragma unroll
        for (int k = 0; k < 16; ++k) a = fmaf(W1[i * 16 + k], x[k], a);
        h[i] = fast_tanh(a);
    }
#pragma unroll
    for (int i = 0; i < 16; ++i) {
        float a = b2[i];
#pragma unroll
        for (int k = 0; k < 16; ++k) a = fmaf(W2[i * 16 + k], h[k], a);
        e[i] = fast_tanh(a);
    }
}

// logit = tanh(qk + Wr @ e) . V
__device__ __forceinline__ float att_logit(const float (&e)[16], const float (&qk)[16],
                                           const float* __restrict__ Wr, const float* __restrict__ V) {
    float a = 0.0f;
#pragma unroll
    for (int i = 0; i < 16; ++i) {
        float r = qk[i];
#pragma unroll
        for (int k = 0; k < 16; ++k) r = fmaf(Wr[i * 16 + k], e[k], r);
        a = fmaf(fast_tanh(r), V[i], a);
    }
    return a;
}

__device__ __forceinline__ float wave_reduce_sum(float v) {
#pragma unroll
    for (int off = 32; off > 0; off >>= 1) v += __shfl_xor(v, off, 64);
    return v;
}

__device__ __forceinline__ void wave_reduce_argmax(float &v, int &idx) {
#pragma unroll
    for (int off = 32; off > 0; off >>= 1) {
        float ov = __shfl_xor(v, off, 64);
        int oi = __shfl_xor(idx, off, 64);
        if (ov > v || (ov == v && oi < idx)) { v = ov; idx = oi; }
    }
}

__device__ __forceinline__ float block_sum(float v) {
    __shared__ float sm[4];
    v = wave_reduce_sum(v);
    __syncthreads();
    if ((threadIdx.x & 63) == 0) sm[threadIdx.x >> 6] = v;
    __syncthreads();
    return sm[0] + sm[1] + sm[2] + sm[3];
}

__device__ __forceinline__ void block_argmax(float &v, int &i) {
    __shared__ float sv[4];
    __shared__ int si[4];
    wave_reduce_argmax(v, i);
    __syncthreads();
    if ((threadIdx.x & 63) == 0) { sv[threadIdx.x >> 6] = v; si[threadIdx.x >> 6] = i; }
    __syncthreads();
    float bv = sv[0]; int bi = si[0];
#pragma unroll
    for (int k = 1; k < 4; ++k)
        if (sv[k] > bv || (sv[k] == bv && si[k] < bi)) { bv = sv[k]; bi = si[k]; }
    v = bv; i = bi;
}

// reduce (l, s[16]) across the block, write 17 floats to dst
__device__ __forceinline__ void block_sum17(float l, float (&s)[16], float* dst) {
    l = wave_reduce_sum(l);
#pragma unroll
    for (int i = 0; i < 16; ++i) s[i] = wave_reduce_sum(s[i]);
    __shared__ float red[4][17];
    int w = threadIdx.x >> 6, ln = threadIdx.x & 63;
    if (ln == 0) {
        red[w][0] = l;
#pragma unroll
        for (int i = 0; i < 16; ++i) red[w][1 + i] = s[i];
    }
    __syncthreads();
    if (threadIdx.x < 17)
        dst[threadIdx.x] = red[0][threadIdx.x] + red[1][threadIdx.x] + red[2][threadIdx.x] + red[3][threadIdx.x];
}

// ---------------------------------------------------------------------------
// K1: embeddings (optionally cached to ws) + glimpse-1 partial sums.
// blocks [0,GB_J) -> jobs, [GB_J,GB_TOT) -> machines.
// ---------------------------------------------------------------------------
template <bool CACHE>
__global__ __launch_bounds__(BLK) void k_emb_g1(Params p) {
    const bool isJob = blockIdx.x < GB_J;
    const float* X  = isJob ? p.jobs : p.machines;
    const float* W1 = isJob ? p.jW1 : p.mW1;
    const float* b1 = isJob ? p.jb1 : p.mb1;
    const float* W2 = isJob ? p.jW2 : p.mW2;
    const float* b2 = isJob ? p.jb2 : p.mb2;
    const float* Wq = isJob ? p.aj_Wq : p.am_Wq;
    const float* bq = isJob ? p.aj_bq : p.am_bq;
    const float* Wr = isJob ? p.aj_Wr : p.am_Wr;
    const float* V  = isJob ? p.aj_V  : p.am_V;
    float* E = isJob ? p.Ej : p.Em;
    const int n  = isJob ? NJ : NM;
    const int nb = isJob ? GB_J : GB_M;
    const int b0 = isJob ? (int)blockIdx.x : (int)blockIdx.x - GB_J;

    // qk = Wq @ last_j + bq (uniform; cheap once per thread)
    float q[16], qk[16];
#pragma unroll
    for (int i = 0; i < 16; ++i) q[i] = p.last_j[i];
#pragma unroll
    for (int i = 0; i < 16; ++i) {
        float a = bq[i];
#pragma unroll
        for (int k = 0; k < 16; ++k) a = fmaf(Wq[i * 16 + k], q[k], a);
        qk[i] = a;
    }

    float l = 0.0f, s[16];
#pragma unroll
    for (int i = 0; i < 16; ++i) s[i] = 0.0f;

    const int stride = nb * BLK;
    for (int r = b0 * BLK + (int)threadIdx.x; r < n; r += stride) {
        float x[16], e[16];
        load16(X, (size_t)r, x);
        emb16(x, W1, b1, W2, b2, e);
        if (CACHE) store16(E, (size_t)r, e);
        float a = att_logit(e, qk, Wr, V);
        // |a| <= sum|V| ~ 0.6 -> exp never overflows; no max-shift needed.
        float pw = __expf(a);
        l += pw;
#pragma unroll
        for (int i = 0; i < 16; ++i) s[i] = fmaf(pw, e[i], s[i]);
    }
    block_sum17(l, s, p.S + (isJob ? P1J : P1M) + (size_t)b0 * 17);
}

// ---------------------------------------------------------------------------
// Combine partials -> g (g1 or g2) -> next-stage qk vector. Single block.
// phase 0: g1 from glimpse1, writes S_QKJA. phase 1: g2 from glimpse2, S_QKMA.
// ---------------------------------------------------------------------------
__global__ __launch_bounds__(BLK) void k_combine_g(Params p, int phase) {
    const float* PJ = p.S + (phase ? P3J : P1J);
    const float* PM = p.S + (phase ? P3M : P1M);
    float accJ[17], accM[17];
#pragma unroll
    for (int c = 0; c < 17; ++c) { accJ[c] = 0.0f; accM[c] = 0.0f; }
    for (int i = threadIdx.x; i < GB_J; i += BLK)
#pragma unroll
        for (int c = 0; c < 17; ++c) accJ[c] += PJ[i * 17 + c];
    for (int i = threadIdx.x; i < GB_M; i += BLK)
#pragma unroll
        for (int c = 0; c < 17; ++c) accM[c] += PM[i * 17 + c];

    __shared__ float totJ[17], totM[17];
    for (int c = 0; c < 17; ++c) {
        float t = block_sum(accJ[c]);
        if (threadIdx.x == 0) totJ[c] = t;
        t = block_sum(accM[c]);
        if (threadIdx.x == 0) totM[c] = t;
    }
    __syncthreads();

    __shared__ float cb[48], gbuf[16];
    if (threadIdx.x < 16) {
        int i = threadIdx.x;
        cb[i]      = phase ? p.S[S_EJS + i] : p.last_j[i];
        cb[16 + i] = totJ[1 + i] / totJ[0];   // softmax-weighted sum / partition
        cb[32 + i] = totM[1 + i] / totM[0];
    }
    __syncthreads();
    const float* gW  = phase ? p.g2W : p.g1W;
    const float* gbv = phase ? p.g2b : p.g1b;
    if (threadIdx.x < 16) {
        int i = threadIdx.x;
        float a = gbv[i];
#pragma unroll
        for (int k = 0; k < 48; ++k) a = fmaf(gW[i * 48 + k], cb[k], a);
        gbuf[i] = fast_tanh(a);
    }
    __syncthreads();
    const float* Wq = phase ? p.ma_Wq : p.ja_Wq;
    const float* bq = phase ? p.ma_bq : p.ja_bq;
    const int off = phase ? S_QKMA : S_QKJA;
    if (threadIdx.x < 16) {
        int i = threadIdx.x;
        float a = bq[i];
#pragma unroll
        for (int k = 0; k < 16; ++k) a = fmaf(Wq[i * 16 + k], gbuf[k], a);
        p.S[off + i] = a;
    }
}

// ---------------------------------------------------------------------------
// K3: job pointer logits -> masked argmax + sum-exp partials
// ---------------------------------------------------------------------------
template <bool CACHE>
__global__ __launch_bounds__(BLK) void k_jlogits(Params p) {
    float qk[16];
#pragma unroll
    for (int i = 0; i < 16; ++i) qk[i] = p.S[S_QKJA + i];

    float best = -3.4e38f;
    int bi = 0x7fffffff;
    float l = 0.0f;
    for (int r = blockIdx.x * BLK + threadIdx.x; r < NJ; r += GB_JL * BLK) {
        float e[16];
        if (CACHE) {
            load16(p.Ej, (size_t)r, e);
        } else {
            float x[16];
            load16(p.jobs, (size_t)r, x);
            emb16(x, p.jW1, p.jb1, p.jW2, p.jb2, e);
        }
        float a = att_logit(e, qk, p.ja_Wr, p.ja_V);
        bool valid = p.mask[r] != 0;
        l += valid ? __expf(a) : 0.0f;     // exp(NEG - max) == 0 in the reference too
        float am = valid ? a : NEGV;
        if (am > best || (am == best && r < bi)) { best = am; bi = r; }
    }
    l = wave_reduce_sum(l);
    wave_reduce_argmax(best, bi);
    __shared__ float rl[4], rv[4];
    __shared__ int ri[4];
    int w = threadIdx.x >> 6, ln = threadIdx.x & 63;
    if (ln == 0) { rl[w] = l; rv[w] = best; ri[w] = bi; }
    __syncthreads();
    if (threadIdx.x == 0) {
        float L = rl[0] + rl[1] + rl[2] + rl[3];
        float v = rv[0]; int i = ri[0];
#pragma unroll
        for (int k = 1; k < 4; ++k)
            if (rv[k] > v || (rv[k] == v && ri[k] < i)) { v = rv[k]; i = ri[k]; }
        p.S[P2V + blockIdx.x] = v;
        p.S[P2I + blockIdx.x] = (float)i;   // exact: i < 2^24
        p.S[P2L + blockIdx.x] = L;
    }
}

// ---------------------------------------------------------------------------
// C2: global argmax over job logits; logp_j; e_js = emb(jobs[sel_j]); qk2j/qk2m
// ---------------------------------------------------------------------------
__global__ __launch_bounds__(BLK) void k_combine2(Params p) {
    float v = -3.4e38f; int vi = 0x7fffffff; float l = 0.0f;
    for (int i = threadIdx.x; i < GB_JL; i += BLK) {
        float pv = p.S[P2V + i];
        int pi = (int)p.S[P2I + i];
        if (pv > v || (pv == v && pi < vi)) { v = pv; vi = pi; }
        l += p.S[P2L + i];
    }
    l = block_sum(l);
    block_argmax(v, vi);
    const int sel = vi;

    __shared__ float xb[16], hb[16], eb[16];
    if (threadIdx.x < 16) xb[threadIdx.x] = p.jobs[(size_t)sel * 16 + threadIdx.x];
    __syncthreads();
    if (threadIdx.x < 16) {
        int i = threadIdx.x;
        float a = p.jb1[i];
#pragma unroll
        for (int k = 0; k < 16; ++k) a = fmaf(p.jW1[i * 16 + k], xb[k], a);
        hb[i] = fast_tanh(a);
    }
    __syncthreads();
    if (threadIdx.x < 16) {
        int i = threadIdx.x;
        float a = p.jb2[i];
#pragma unroll
        for (int k = 0; k < 16; ++k) a = fmaf(p.jW2[i * 16 + k], hb[k], a);
        float e = fast_tanh(a);
        eb[i] = e;
        p.S[S_EJS + i] = e;
    }
    __syncthreads();
    if (threadIdx.x < 16) {
        int i = threadIdx.x;
        float a1 = p.aj_bq[i], a2 = p.am_bq[i];
#pragma unroll
        for (int k = 0; k < 16; ++k) {
            a1 = fmaf(p.aj_Wq[i * 16 + k], eb[k], a1);
            a2 = fmaf(p.am_Wq[i * 16 + k], eb[k], a2);
        }
        p.S[S_QK2J + i] = a1;
        p.S[S_QK2M + i] = a2;
    }
    if (threadIdx.x == 0) {
        p.S[S_LOGPJ] = v - logf(l);     // log_softmax at the argmax
        p.S[S_SELJ] = (float)sel;
    }
}

// ---------------------------------------------------------------------------
// K4: glimpse-2 over jobs (aj_*) and machines (am_*) with query e_js
// ---------------------------------------------------------------------------
template <bool CACHE>
__global__ __launch_bounds__(BLK) void k_glimpse2(Params p) {
    const bool isJob = blockIdx.x < GB_J;
    const float* Wr = isJob ? p.aj_Wr : p.am_Wr;
    const float* V  = isJob ? p.aj_V  : p.am_V;
    const float* E  = isJob ? p.Ej : p.Em;
    const float* X  = isJob ? p.jobs : p.machines;
    const float* W1 = isJob ? p.jW1 : p.mW1;
    const float* b1 = isJob ? p.jb1 : p.mb1;
    const float* W2 = isJob ? p.jW2 : p.mW2;
    const float* b2 = isJob ? p.jb2 : p.mb2;
    const int n  = isJob ? NJ : NM;
    const int nb = isJob ? GB_J : GB_M;
    const int b0 = isJob ? (int)blockIdx.x : (int)blockIdx.x - GB_J;
    const int qoff = isJob ? S_QK2J : S_QK2M;

    float qk[16];
#pragma unroll
    for (int i = 0; i < 16; ++i) qk[i] = p.S[qoff + i];

    float l = 0.0f, s[16];
#pragma unroll
    for (int i = 0; i < 16; ++i) s[i] = 0.0f;

    const int stride = nb * BLK;
    for (int r = b0 * BLK + (int)threadIdx.x; r < n; r += stride) {
        float e[16];
        if (CACHE) {
            load16(E, (size_t)r, e);
        } else {
            float x[16];
            load16(X, (size_t)r, x);
            emb16(x, W1, b1, W2, b2, e);
        }
        float a = att_logit(e, qk, Wr, V);
        float pw = __expf(a);
        l += pw;
#pragma unroll
        for (int i = 0; i < 16; ++i) s[i] = fmaf(pw, e[i], s[i]);
    }
    block_sum17(l, s, p.S + (isJob ? P3J : P3M) + (size_t)b0 * 17);
}

// ---------------------------------------------------------------------------
// K5: machine logits -> argmax + sum-exp partials
// ---------------------------------------------------------------------------
template <bool CACHE>
__global__ __launch_bounds__(BLK) void k_mlogits(Params p) {
    float qk[16];
#pragma unroll
    for (int i = 0; i < 16; ++i) qk[i] = p.S[S_QKMA + i];

    float best = -3.4e38f;
    int bi = 0x7fffffff;
    float l = 0.0f;
    for (int r = blockIdx.x * BLK + threadIdx.x; r < NM; r += GB_ML * BLK) {
        float e[16];
        if (CACHE) {
            load16(p.Em, (size_t)r, e);
        } else {
            float x[16];
            load16(p.machines, (size_t)r, x);
            emb16(x, p.mW1, p.mb1, p.mW2, p.mb2, e);
        }
        float a = att_logit(e, qk, p.ma_Wr, p.ma_V);
        l += __expf(a);
        if (a > best || (a == best && r < bi)) { best = a; bi = r; }
    }
    l = wave_reduce_sum(l);
    wave_reduce_argmax(best, bi);
    __shared__ float rl[4], rv[4];
    __shared__ int ri[4];
    int w = threadIdx.x >> 6, ln = threadIdx.x & 63;
    if (ln == 0) { rl[w] = l; rv[w] = best; ri[w] = bi; }
    __syncthreads();
    if (threadIdx.x == 0) {
        float L = rl[0] + rl[1] + rl[2] + rl[3];
        float v = rv[0]; int i = ri[0];
#pragma unroll
        for (int k = 1; k < 4; ++k)
            if (rv[k] > v || (rv[k] == v && ri[k] < i)) { v = rv[k]; i = ri[k]; }
        p.S[P4V + blockIdx.x] = v;
        p.S[P4I + blockIdx.x] = (float)i;
        p.S[P4L + blockIdx.x] = L;
    }
}

// ---------------------------------------------------------------------------
// C4: final combine -> outputs [sel_j, sel_m, logpas] as float32
// ---------------------------------------------------------------------------
__global__ __launch_bounds__(BLK) void k_combine4(Params p) {
    float v = -3.4e38f; int vi = 0x7fffffff; float l = 0.0f;
    for (int i = threadIdx.x; i < GB_ML; i += BLK) {
        float pv = p.S[P4V + i];
        int pi = (int)p.S[P4I + i];
        if (pv > v || (pv == v && pi < vi)) { v = pv; vi = pi; }
        l += p.S[P4L + i];
    }
    l = block_sum(l);
    block_argmax(v, vi);
    if (threadIdx.x == 0) {
        p.out[0] = p.S[S_SELJ];
        p.out[1] = (float)vi;
        p.out[2] = p.S[S_LOGPJ] + (v - logf(l));
    }
}

// ---------------------------------------------------------------------------
extern "C" void kernel_launch(void* const* d_in, const int* in_sizes, int n_in,
                              void* d_out, int out_size, void* d_ws, size_t ws_size,
                              hipStream_t stream) {
    Params p;
    p.jobs     = (const float*)d_in[0];
    p.machines = (const float*)d_in[1];
    p.mask     = (const int*)d_in[2];
    p.jW1 = (const float*)d_in[3];  p.jb1 = (const float*)d_in[4];
    p.jW2 = (const float*)d_in[5];  p.jb2 = (const float*)d_in[6];
    p.mW1 = (const float*)d_in[7];  p.mb1 = (const float*)d_in[8];
    p.mW2 = (const float*)d_in[9];  p.mb2 = (const float*)d_in[10];
    p.aj_Wq = (const float*)d_in[11]; p.aj_bq = (const float*)d_in[12];
    p.aj_Wr = (const float*)d_in[13]; p.aj_V  = (const float*)d_in[14];
    p.am_Wq = (const float*)d_in[15]; p.am_bq = (const float*)d_in[16];
    p.am_Wr = (const float*)d_in[17]; p.am_V  = (const float*)d_in[18];
    p.ja_Wq = (const float*)d_in[19]; p.ja_bq = (const float*)d_in[20];
    p.ja_Wr = (const float*)d_in[21]; p.ja_V  = (const float*)d_in[22];
    p.ma_Wq = (const float*)d_in[23]; p.ma_bq = (const float*)d_in[24];
    p.ma_Wr = (const float*)d_in[25]; p.ma_V  = (const float*)d_in[26];
    p.g1W = (const float*)d_in[27]; p.g1b = (const float*)d_in[28];
    p.g2W = (const float*)d_in[29]; p.g2b = (const float*)d_in[30];
    p.last_j = (const float*)d_in[31];
    p.S = (float*)d_ws;
    p.Ej = (float*)d_ws + E_OFF;
    p.Em = p.Ej + (size_t)NJ * 16;
    p.out = (float*)d_out;

    const size_t needed = (E_OFF + (size_t)(NJ + NM) * 16) * sizeof(float);
    const bool cache = ws_size >= needed;

    if (cache) {
        k_emb_g1<true><<<GB_TOT, BLK, 0, stream>>>(p);
        k_combine_g<<<1, BLK, 0, stream>>>(p, 0);
        k_jlogits<true><<<GB_JL, BLK, 0, stream>>>(p);
        k_combine2<<<1, BLK, 0, stream>>>(p);
        k_glimpse2<true><<<GB_TOT, BLK, 0, stream>>>(p);
        k_combine_g<<<1, BLK, 0, stream>>>(p, 1);
        k_mlogits<true><<<GB_ML, BLK, 0, stream>>>(p);
        k_combine4<<<1, BLK, 0, stream>>>(p);
    } else {
        k_emb_g1<false><<<GB_TOT, BLK, 0, stream>>>(p);
        k_combine_g<<<1, BLK, 0, stream>>>(p, 0);
        k_jlogits<false><<<GB_JL, BLK, 0, stream>>>(p);
        k_combine2<<<1, BLK, 0, stream>>>(p);
        k_glimpse2<false><<<GB_TOT, BLK, 0, stream>>>(p);
        k_combine_g<<<1, BLK, 0, stream>>>(p, 1);
        k_mlogits<false><<<GB_ML, BLK, 0, stream>>>(p);
        k_combine4<<<1, BLK, 0, stream>>>(p);
    }
}

// Round 2
// 382.748 us; speedup vs baseline: 1.2235x; 1.2235x over previous
//
#include <hip/hip_runtime.h>
#include <cstddef>
#include <cstdint>

// ---------------------------------------------------------------------------
// attention_net_noc: pointer-network decode step.
// R2: latency-hiding rework. Round-1 counters showed k_emb_g1 at VALUBusy
// 31.5%, occupancy 44% (grid-capped at 50%), VGPR=40 (compiler serialized the
// FMA chains). Fix: (a) 2 rows/thread with manually interleaved chains ->
// ILP x2 and half the s_load:FMA ratio; (b) single-pass grids sized to the
// data (no 1024-block cap). fp32 throughout (argmax must match numpy fp32
// reference; no fp32 MFMA on CDNA4 anyway).
// ---------------------------------------------------------------------------

constexpr int NJ = 1000000;
constexpr int NM = 500000;
constexpr float NEGV = -1e8f;

constexpr int BLK = 256;
constexpr int ROWS_PER_BLK = 512;            // 2 rows per thread
constexpr int GB_J2 = (NJ + ROWS_PER_BLK - 1) / ROWS_PER_BLK;  // 1954
constexpr int GB_M2 = (NM + ROWS_PER_BLK - 1) / ROWS_PER_BLK;  // 977
constexpr int GB_TOT2 = GB_J2 + GB_M2;                          // 2931

// ---- workspace layout (float offsets from start of d_ws) ----
// Phase-2 partials reuse the phase-1 buffers (consumed before overwrite).
constexpr int S_QKJA = 0;    // 16: ja_Wq@g1 + ja_bq
constexpr int S_QK2J = 16;   // 16: aj_Wq@e_js + aj_bq
constexpr int S_QK2M = 32;   // 16: am_Wq@e_js + am_bq
constexpr int S_EJS  = 48;   // 16: E_j[sel_j]
constexpr int S_QKMA = 64;   // 16: ma_Wq@g2 + ma_bq
constexpr int S_LOGPJ = 80;
constexpr int S_SELJ  = 81;  // stored as float (exact, < 2^24)
constexpr int P1J = 96;                        // GB_J2*17 glimpse partials (l, s[16])
constexpr int P1M = P1J + GB_J2 * 17;          // GB_M2*17
constexpr int P2V = P1M + GB_M2 * 17;          // GB_J2 argmax vals (mlogits reuses, GB_M2<=GB_J2)
constexpr int P2I = P2V + GB_J2;
constexpr int P2L = P2I + GB_J2;
constexpr size_t E_OFF = 65536;                // float offset of E_j cache (256KB in)
static_assert(P2L + GB_J2 <= (int)E_OFF, "partials overflow into E cache");

struct Params {
    const float *jobs, *machines;
    const int *mask;
    const float *jW1, *jb1, *jW2, *jb2;
    const float *mW1, *mb1, *mW2, *mb2;
    const float *aj_Wq, *aj_bq, *aj_Wr, *aj_V;
    const float *am_Wq, *am_bq, *am_Wr, *am_V;
    const float *ja_Wq, *ja_bq, *ja_Wr, *ja_V;
    const float *ma_Wq, *ma_bq, *ma_Wr, *ma_V;
    const float *g1W, *g1b, *g2W, *g2b, *last_j;
    float *S;        // smalls + partials (in ws)
    float *Ej, *Em;  // embedding cache (in ws; valid only if CACHE)
    float *out;
};

// ---------------------------------------------------------------------------
// device helpers
// ---------------------------------------------------------------------------

// tanh(x) = 1 - 2/(e^{2x}+1). |x| <= ~3 here; abs err ~2e-7 vs np.tanh.
__device__ __forceinline__ float fast_tanh(float x) {
    float e = __expf(2.0f * x);
    return 1.0f - __fdividef(2.0f, e + 1.0f);
}

__device__ __forceinline__ void load16(const float* __restrict__ X, size_t r, float (&x)[16]) {
    const float4* p4 = reinterpret_cast<const float4*>(X) + r * 4;
    float4 a = p4[0], b = p4[1], c = p4[2], d = p4[3];
    x[0]=a.x; x[1]=a.y; x[2]=a.z; x[3]=a.w;
    x[4]=b.x; x[5]=b.y; x[6]=b.z; x[7]=b.w;
    x[8]=c.x; x[9]=c.y; x[10]=c.z; x[11]=c.w;
    x[12]=d.x; x[13]=d.y; x[14]=d.z; x[15]=d.w;
}

__device__ __forceinline__ void store16(float* __restrict__ X, size_t r, const float (&x)[16]) {
    float4* p4 = reinterpret_cast<float4*>(X) + r * 4;
    p4[0] = make_float4(x[0], x[1], x[2], x[3]);
    p4[1] = make_float4(x[4], x[5], x[6], x[7]);
    p4[2] = make_float4(x[8], x[9], x[10], x[11]);
    p4[3] = make_float4(x[12], x[13], x[14], x[15]);
}

// Two-row interleaved MLP: every weight load feeds two independent chains.
__device__ __forceinline__ void emb16_2(const float (&x0)[16], const float (&x1)[16],
                                        const float* __restrict__ W1, const float* __restrict__ b1,
                                        const float* __restrict__ W2, const float* __restrict__ b2,
                                        float (&e0)[16], float (&e1)[16]) {
    float h0[16], h1[16];
#pragma unroll
    for (int i = 0; i < 16; ++i) {
        float a0 = b1[i], a1 = a0;
#pragma unroll
        for (int k = 0; k < 16; ++k) {
            float w = W1[i * 16 + k];
            a0 = fmaf(w, x0[k], a0);
            a1 = fmaf(w, x1[k], a1);
        }
        h0[i] = fast_tanh(a0);
        h1[i] = fast_tanh(a1);
    }
#pragma unroll
    for (int i = 0; i < 16; ++i) {
        float a0 = b2[i], a1 = a0;
#pragma unroll
        for (int k = 0; k < 16; ++k) {
            float w = W2[i * 16 + k];
            a0 = fmaf(w, h0[k], a0);
            a1 = fmaf(w, h1[k], a1);
        }
        e0[i] = fast_tanh(a0);
        e1[i] = fast_tanh(a1);
    }
}

__device__ __forceinline__ void att_logit_2(const float (&e0)[16], const float (&e1)[16],
                                            const float (&qk)[16],
                                            const float* __restrict__ Wr, const float* __restrict__ V,
                                            float &out0, float &out1) {
    float a0 = 0.0f, a1 = 0.0f;
#pragma unroll
    for (int i = 0; i < 16; ++i) {
        float r0 = qk[i], r1 = qk[i];
#pragma unroll
        for (int k = 0; k < 16; ++k) {
            float w = Wr[i * 16 + k];
            r0 = fmaf(w, e0[k], r0);
            r1 = fmaf(w, e1[k], r1);
        }
        float v = V[i];
        a0 = fmaf(fast_tanh(r0), v, a0);
        a1 = fmaf(fast_tanh(r1), v, a1);
    }
    out0 = a0;
    out1 = a1;
}

__device__ __forceinline__ float wave_reduce_sum(float v) {
#pragma unroll
    for (int off = 32; off > 0; off >>= 1) v += __shfl_xor(v, off, 64);
    return v;
}

__device__ __forceinline__ void wave_reduce_argmax(float &v, int &idx) {
#pragma unroll
    for (int off = 32; off > 0; off >>= 1) {
        float ov = __shfl_xor(v, off, 64);
        int oi = __shfl_xor(idx, off, 64);
        if (ov > v || (ov == v && oi < idx)) { v = ov; idx = oi; }
    }
}

__device__ __forceinline__ float block_sum(float v) {
    __shared__ float sm[4];
    v = wave_reduce_sum(v);
    __syncthreads();
    if ((threadIdx.x & 63) == 0) sm[threadIdx.x >> 6] = v;
    __syncthreads();
    return sm[0] + sm[1] + sm[2] + sm[3];
}

__device__ __forceinline__ void block_argmax(float &v, int &i) {
    __shared__ float sv[4];
    __shared__ int si[4];
    wave_reduce_argmax(v, i);
    __syncthreads();
    if ((threadIdx.x & 63) == 0) { sv[threadIdx.x >> 6] = v; si[threadIdx.x >> 6] = i; }
    __syncthreads();
    float bv = sv[0]; int bi = si[0];
#pragma unroll
    for (int k = 1; k < 4; ++k)
        if (sv[k] > bv || (sv[k] == bv && si[k] < bi)) { bv = sv[k]; bi = si[k]; }
    v = bv; i = bi;
}

// reduce (l, s[16]) across the block, write 17 floats to dst
__device__ __forceinline__ void block_sum17(float l, float (&s)[16], float* dst) {
    l = wave_reduce_sum(l);
#pragma unroll
    for (int i = 0; i < 16; ++i) s[i] = wave_reduce_sum(s[i]);
    __shared__ float red[4][17];
    int w = threadIdx.x >> 6, ln = threadIdx.x & 63;
    if (ln == 0) {
        red[w][0] = l;
#pragma unroll
        for (int i = 0; i < 16; ++i) red[w][1 + i] = s[i];
    }
    __syncthreads();
    if (threadIdx.x < 17)
        dst[threadIdx.x] = red[0][threadIdx.x] + red[1][threadIdx.x] + red[2][threadIdx.x] + red[3][threadIdx.x];
}

// ---------------------------------------------------------------------------
// K1: embeddings (optionally cached to ws) + glimpse-1 partial sums.
// blocks [0,GB_J2) -> jobs, [GB_J2,GB_TOT2) -> machines. 2 rows/thread.
// ---------------------------------------------------------------------------
template <bool CACHE>
__global__ __launch_bounds__(BLK) void k_emb_g1(Params p) {
    const bool isJob = blockIdx.x < GB_J2;
    const float* X  = isJob ? p.jobs : p.machines;
    const float* W1 = isJob ? p.jW1 : p.mW1;
    const float* b1 = isJob ? p.jb1 : p.mb1;
    const float* W2 = isJob ? p.jW2 : p.mW2;
    const float* b2 = isJob ? p.jb2 : p.mb2;
    const float* Wq = isJob ? p.aj_Wq : p.am_Wq;
    const float* bq = isJob ? p.aj_bq : p.am_bq;
    const float* Wr = isJob ? p.aj_Wr : p.am_Wr;
    const float* V  = isJob ? p.aj_V  : p.am_V;
    float* E = isJob ? p.Ej : p.Em;
    const int n  = isJob ? NJ : NM;
    const int b0 = isJob ? (int)blockIdx.x : (int)blockIdx.x - GB_J2;

    // qk = Wq @ last_j + bq (uniform)
    float q[16], qk[16];
#pragma unroll
    for (int i = 0; i < 16; ++i) q[i] = p.last_j[i];
#pragma unroll
    for (int i = 0; i < 16; ++i) {
        float a = bq[i];
#pragma unroll
        for (int k = 0; k < 16; ++k) a = fmaf(Wq[i * 16 + k], q[k], a);
        qk[i] = a;
    }

    const int r0 = b0 * ROWS_PER_BLK + (int)threadIdx.x;
    const int r1 = r0 + BLK;
    const bool v0 = r0 < n, v1 = r1 < n;
    const size_t a0 = (size_t)(v0 ? r0 : 0);
    const size_t a1 = (size_t)(v1 ? r1 : 0);

    float x0[16], x1[16], e0[16], e1[16];
    load16(X, a0, x0);
    load16(X, a1, x1);
    emb16_2(x0, x1, W1, b1, W2, b2, e0, e1);
    if (CACHE) {
        if (v0) store16(E, a0, e0);
        if (v1) store16(E, a1, e1);
    }
    float lg0, lg1;
    att_logit_2(e0, e1, qk, Wr, V, lg0, lg1);
    // |logit| <= sum|V| ~ 0.6 -> exp never overflows; no max-shift needed.
    float pw0 = v0 ? __expf(lg0) : 0.0f;
    float pw1 = v1 ? __expf(lg1) : 0.0f;
    float l = pw0 + pw1, s[16];
#pragma unroll
    for (int i = 0; i < 16; ++i) s[i] = fmaf(pw0, e0[i], pw1 * e1[i]);

    block_sum17(l, s, p.S + (isJob ? P1J : P1M) + (size_t)b0 * 17);
}

// ---------------------------------------------------------------------------
// Combine partials -> g (g1 or g2) -> next-stage qk vector. Single block.
// ---------------------------------------------------------------------------
__global__ __launch_bounds__(BLK) void k_combine_g(Params p, int phase) {
    const float* PJ = p.S + P1J;
    const float* PM = p.S + P1M;
    float accJ[17], accM[17];
#pragma unroll
    for (int c = 0; c < 17; ++c) { accJ[c] = 0.0f; accM[c] = 0.0f; }
    for (int i = threadIdx.x; i < GB_J2; i += BLK)
#pragma unroll
        for (int c = 0; c < 17; ++c) accJ[c] += PJ[i * 17 + c];
    for (int i = threadIdx.x; i < GB_M2; i += BLK)
#pragma unroll
        for (int c = 0; c < 17; ++c) accM[c] += PM[i * 17 + c];

    __shared__ float totJ[17], totM[17];
    for (int c = 0; c < 17; ++c) {
        float t = block_sum(accJ[c]);
        if (threadIdx.x == 0) totJ[c] = t;
        t = block_sum(accM[c]);
        if (threadIdx.x == 0) totM[c] = t;
    }
    __syncthreads();

    __shared__ float cb[48], gbuf[16];
    if (threadIdx.x < 16) {
        int i = threadIdx.x;
        cb[i]      = phase ? p.S[S_EJS + i] : p.last_j[i];
        cb[16 + i] = totJ[1 + i] / totJ[0];   // softmax-weighted sum / partition
        cb[32 + i] = totM[1 + i] / totM[0];
    }
    __syncthreads();
    const float* gW  = phase ? p.g2W : p.g1W;
    const float* gbv = phase ? p.g2b : p.g1b;
    if (threadIdx.x < 16) {
        int i = threadIdx.x;
        float a = gbv[i];
#pragma unroll
        for (int k = 0; k < 48; ++k) a = fmaf(gW[i * 48 + k], cb[k], a);
        gbuf[i] = fast_tanh(a);
    }
    __syncthreads();
    const float* Wq = phase ? p.ma_Wq : p.ja_Wq;
    const float* bq = phase ? p.ma_bq : p.ja_bq;
    const int off = phase ? S_QKMA : S_QKJA;
    if (threadIdx.x < 16) {
        int i = threadIdx.x;
        float a = bq[i];
#pragma unroll
        for (int k = 0; k < 16; ++k) a = fmaf(Wq[i * 16 + k], gbuf[k], a);
        p.S[off + i] = a;
    }
}

// ---------------------------------------------------------------------------
// K3: job pointer logits -> masked argmax + sum-exp partials. 2 rows/thread.
// ---------------------------------------------------------------------------
template <bool CACHE>
__global__ __launch_bounds__(BLK) void k_jlogits(Params p) {
    float qk[16];
#pragma unroll
    for (int i = 0; i < 16; ++i) qk[i] = p.S[S_QKJA + i];

    const int r0 = blockIdx.x * ROWS_PER_BLK + (int)threadIdx.x;
    const int r1 = r0 + BLK;
    const bool v0 = r0 < NJ, v1 = r1 < NJ;
    const size_t a0 = (size_t)(v0 ? r0 : 0);
    const size_t a1 = (size_t)(v1 ? r1 : 0);

    float e0[16], e1[16];
    if (CACHE) {
        load16(p.Ej, a0, e0);
        load16(p.Ej, a1, e1);
    } else {
        float x0[16], x1[16];
        load16(p.jobs, a0, x0);
        load16(p.jobs, a1, x1);
        emb16_2(x0, x1, p.jW1, p.jb1, p.jW2, p.jb2, e0, e1);
    }
    float lg0, lg1;
    att_logit_2(e0, e1, qk, p.ja_Wr, p.ja_V, lg0, lg1);
    const bool m0 = v0 && (p.mask[a0] != 0);
    const bool m1 = v1 && (p.mask[a1] != 0);
    float l = (m0 ? __expf(lg0) : 0.0f) + (m1 ? __expf(lg1) : 0.0f);
    float am0 = m0 ? lg0 : NEGV - 1.0f;   // invalid rows also below masked NEG
    float am1 = m1 ? lg1 : NEGV - 1.0f;
    float best;
    int bi;
    if (am0 >= am1) { best = am0; bi = r0; }
    else            { best = am1; bi = r1; }

    l = wave_reduce_sum(l);
    wave_reduce_argmax(best, bi);
    __shared__ float rl[4], rv[4];
    __shared__ int ri[4];
    int w = threadIdx.x >> 6, ln = threadIdx.x & 63;
    if (ln == 0) { rl[w] = l; rv[w] = best; ri[w] = bi; }
    __syncthreads();
    if (threadIdx.x == 0) {
        float L = rl[0] + rl[1] + rl[2] + rl[3];
        float v = rv[0]; int i = ri[0];
#pragma unroll
        for (int k = 1; k < 4; ++k)
            if (rv[k] > v || (rv[k] == v && ri[k] < i)) { v = rv[k]; i = ri[k]; }
        p.S[P2V + blockIdx.x] = v;
        p.S[P2I + blockIdx.x] = (float)i;   // exact: i < 2^24
        p.S[P2L + blockIdx.x] = L;
    }
}

// ---------------------------------------------------------------------------
// C2: global argmax over job logits; logp_j; e_js = emb(jobs[sel_j]); qk2j/qk2m
// ---------------------------------------------------------------------------
__global__ __launch_bounds__(BLK) void k_combine2(Params p) {
    float v = -3.4e38f; int vi = 0x7fffffff; float l = 0.0f;
    for (int i = threadIdx.x; i < GB_J2; i += BLK) {
        float pv = p.S[P2V + i];
        int pi = (int)p.S[P2I + i];
        if (pv > v || (pv == v && pi < vi)) { v = pv; vi = pi; }
        l += p.S[P2L + i];
    }
    l = block_sum(l);
    block_argmax(v, vi);
    const int sel = vi;

    __shared__ float xb[16], hb[16], eb[16];
    if (threadIdx.x < 16) xb[threadIdx.x] = p.jobs[(size_t)sel * 16 + threadIdx.x];
    __syncthreads();
    if (threadIdx.x < 16) {
        int i = threadIdx.x;
        float a = p.jb1[i];
#pragma unroll
        for (int k = 0; k < 16; ++k) a = fmaf(p.jW1[i * 16 + k], xb[k], a);
        hb[i] = fast_tanh(a);
    }
    __syncthreads();
    if (threadIdx.x < 16) {
        int i = threadIdx.x;
        float a = p.jb2[i];
#pragma unroll
        for (int k = 0; k < 16; ++k) a = fmaf(p.jW2[i * 16 + k], hb[k], a);
        float e = fast_tanh(a);
        eb[i] = e;
        p.S[S_EJS + i] = e;
    }
    __syncthreads();
    if (threadIdx.x < 16) {
        int i = threadIdx.x;
        float a1 = p.aj_bq[i], a2 = p.am_bq[i];
#pragma unroll
        for (int k = 0; k < 16; ++k) {
            a1 = fmaf(p.aj_Wq[i * 16 + k], eb[k], a1);
            a2 = fmaf(p.am_Wq[i * 16 + k], eb[k], a2);
        }
        p.S[S_QK2J + i] = a1;
        p.S[S_QK2M + i] = a2;
    }
    if (threadIdx.x == 0) {
        p.S[S_LOGPJ] = v - logf(l);     // log_softmax at the argmax
        p.S[S_SELJ] = (float)sel;
    }
}

// ---------------------------------------------------------------------------
// K4: glimpse-2 over jobs (aj_*) and machines (am_*), query e_js. 2 rows/thread.
// Writes partials into the (already consumed) P1 buffers.
// ---------------------------------------------------------------------------
template <bool CACHE>
__global__ __launch_bounds__(BLK) void k_glimpse2(Params p) {
    const bool isJob = blockIdx.x < GB_J2;
    const float* Wr = isJob ? p.aj_Wr : p.am_Wr;
    const float* V  = isJob ? p.aj_V  : p.am_V;
    const float* E  = isJob ? p.Ej : p.Em;
    const float* X  = isJob ? p.jobs : p.machines;
    const float* W1 = isJob ? p.jW1 : p.mW1;
    const float* b1 = isJob ? p.jb1 : p.mb1;
    const float* W2 = isJob ? p.jW2 : p.mW2;
    const float* b2 = isJob ? p.jb2 : p.mb2;
    const int n  = isJob ? NJ : NM;
    const int b0 = isJob ? (int)blockIdx.x : (int)blockIdx.x - GB_J2;
    const int qoff = isJob ? S_QK2J : S_QK2M;

    float qk[16];
#pragma unroll
    for (int i = 0; i < 16; ++i) qk[i] = p.S[qoff + i];

    const int r0 = b0 * ROWS_PER_BLK + (int)threadIdx.x;
    const int r1 = r0 + BLK;
    const bool v0 = r0 < n, v1 = r1 < n;
    const size_t a0 = (size_t)(v0 ? r0 : 0);
    const size_t a1 = (size_t)(v1 ? r1 : 0);

    float e0[16], e1[16];
    if (CACHE) {
        load16(E, a0, e0);
        load16(E, a1, e1);
    } else {
        float x0[16], x1[16];
        load16(X, a0, x0);
        load16(X, a1, x1);
        emb16_2(x0, x1, W1, b1, W2, b2, e0, e1);
    }
    float lg0, lg1;
    att_logit_2(e0, e1, qk, Wr, V, lg0, lg1);
    float pw0 = v0 ? __expf(lg0) : 0.0f;
    float pw1 = v1 ? __expf(lg1) : 0.0f;
    float l = pw0 + pw1, s[16];
#pragma unroll
    for (int i = 0; i < 16; ++i) s[i] = fmaf(pw0, e0[i], pw1 * e1[i]);

    block_sum17(l, s, p.S + (isJob ? P1J : P1M) + (size_t)b0 * 17);
}

// ---------------------------------------------------------------------------
// K5: machine logits -> argmax + sum-exp partials. 2 rows/thread.
// Writes into the (already consumed) P2 buffers.
// ---------------------------------------------------------------------------
template <bool CACHE>
__global__ __launch_bounds__(BLK) void k_mlogits(Params p) {
    float qk[16];
#pragma unroll
    for (int i = 0; i < 16; ++i) qk[i] = p.S[S_QKMA + i];

    const int r0 = blockIdx.x * ROWS_PER_BLK + (int)threadIdx.x;
    const int r1 = r0 + BLK;
    const bool v0 = r0 < NM, v1 = r1 < NM;
    const size_t a0 = (size_t)(v0 ? r0 : 0);
    const size_t a1 = (size_t)(v1 ? r1 : 0);

    float e0[16], e1[16];
    if (CACHE) {
        load16(p.Em, a0, e0);
        load16(p.Em, a1, e1);
    } else {
        float x0[16], x1[16];
        load16(p.machines, a0, x0);
        load16(p.machines, a1, x1);
        emb16_2(x0, x1, p.mW1, p.mb1, p.mW2, p.mb2, e0, e1);
    }
    float lg0, lg1;
    att_logit_2(e0, e1, qk, p.ma_Wr, p.ma_V, lg0, lg1);
    float l = (v0 ? __expf(lg0) : 0.0f) + (v1 ? __expf(lg1) : 0.0f);
    float am0 = v0 ? lg0 : -3.4e38f;
    float am1 = v1 ? lg1 : -3.4e38f;
    float best;
    int bi;
    if (am0 >= am1) { best = am0; bi = r0; }
    else            { best = am1; bi = r1; }

    l = wave_reduce_sum(l);
    wave_reduce_argmax(best, bi);
    __shared__ float rl[4], rv[4];
    __shared__ int ri[4];
    int w = threadIdx.x >> 6, ln = threadIdx.x & 63;
    if (ln == 0) { rl[w] = l; rv[w] = best; ri[w] = bi; }
    __syncthreads();
    if (threadIdx.x == 0) {
        float L = rl[0] + rl[1] + rl[2] + rl[3];
        float v = rv[0]; int i = ri[0];
#pragma unroll
        for (int k = 1; k < 4; ++k)
            if (rv[k] > v || (rv[k] == v && ri[k] < i)) { v = rv[k]; i = ri[k]; }
        p.S[P2V + blockIdx.x] = v;
        p.S[P2I + blockIdx.x] = (float)i;
        p.S[P2L + blockIdx.x] = L;
    }
}

// ---------------------------------------------------------------------------
// C4: final combine -> outputs [sel_j, sel_m, logpas] as float32
// ---------------------------------------------------------------------------
__global__ __launch_bounds__(BLK) void k_combine4(Params p) {
    float v = -3.4e38f; int vi = 0x7fffffff; float l = 0.0f;
    for (int i = threadIdx.x; i < GB_M2; i += BLK) {
        float pv = p.S[P2V + i];
        int pi = (int)p.S[P2I + i];
        if (pv > v || (pv == v && pi < vi)) { v = pv; vi = pi; }
        l += p.S[P2L + i];
    }
    l = block_sum(l);
    block_argmax(v, vi);
    if (threadIdx.x == 0) {
        p.out[0] = p.S[S_SELJ];
        p.out[1] = (float)vi;
        p.out[2] = p.S[S_LOGPJ] + (v - logf(l));
    }
}

// ---------------------------------------------------------------------------
extern "C" void kernel_launch(void* const* d_in, const int* in_sizes, int n_in,
                              void* d_out, int out_size, void* d_ws, size_t ws_size,
                              hipStream_t stream) {
    Params p;
    p.jobs     = (const float*)d_in[0];
    p.machines = (const float*)d_in[1];
    p.mask     = (const int*)d_in[2];
    p.jW1 = (const float*)d_in[3];  p.jb1 = (const float*)d_in[4];
    p.jW2 = (const float*)d_in[5];  p.jb2 = (const float*)d_in[6];
    p.mW1 = (const float*)d_in[7];  p.mb1 = (const float*)d_in[8];
    p.mW2 = (const float*)d_in[9];  p.mb2 = (const float*)d_in[10];
    p.aj_Wq = (const float*)d_in[11]; p.aj_bq = (const float*)d_in[12];
    p.aj_Wr = (const float*)d_in[13]; p.aj_V  = (const float*)d_in[14];
    p.am_Wq = (const float*)d_in[15]; p.am_bq = (const float*)d_in[16];
    p.am_Wr = (const float*)d_in[17]; p.am_V  = (const float*)d_in[18];
    p.ja_Wq = (const float*)d_in[19]; p.ja_bq = (const float*)d_in[20];
    p.ja_Wr = (const float*)d_in[21]; p.ja_V  = (const float*)d_in[22];
    p.ma_Wq = (const float*)d_in[23]; p.ma_bq = (const float*)d_in[24];
    p.ma_Wr = (const float*)d_in[25]; p.ma_V  = (const float*)d_in[26];
    p.g1W = (const float*)d_in[27]; p.g1b = (const float*)d_in[28];
    p.g2W = (const float*)d_in[29]; p.g2b = (const float*)d_in[30];
    p.last_j = (const float*)d_in[31];
    p.S = (float*)d_ws;
    p.Ej = (float*)d_ws + E_OFF;
    p.Em = p.Ej + (size_t)NJ * 16;
    p.out = (float*)d_out;

    const size_t needed = (E_OFF + (size_t)(NJ + NM) * 16) * sizeof(float);
    const bool cache = ws_size >= needed;

    if (cache) {
        k_emb_g1<true><<<GB_TOT2, BLK, 0, stream>>>(p);
        k_combine_g<<<1, BLK, 0, stream>>>(p, 0);
        k_jlogits<true><<<GB_J2, BLK, 0, stream>>>(p);
        k_combine2<<<1, BLK, 0, stream>>>(p);
        k_glimpse2<true><<<GB_TOT2, BLK, 0, stream>>>(p);
        k_combine_g<<<1, BLK, 0, stream>>>(p, 1);
        k_mlogits<true><<<GB_M2, BLK, 0, stream>>>(p);
        k_combine4<<<1, BLK, 0, stream>>>(p);
    } else {
        k_emb_g1<false><<<GB_TOT2, BLK, 0, stream>>>(p);
        k_combine_g<<<1, BLK, 0, stream>>>(p, 0);
        k_jlogits<false><<<GB_J2, BLK, 0, stream>>>(p);
        k_combine2<<<1, BLK, 0, stream>>>(p);
        k_glimpse2<false><<<GB_TOT2, BLK, 0, stream>>>(p);
        k_combine_g<<<1, BLK, 0, stream>>>(p, 1);
        k_mlogits<false><<<GB_M2, BLK, 0, stream>>>(p);
        k_combine4<<<1, BLK, 0, stream>>>(p);
    }
}

// Round 3
// 341.994 us; speedup vs baseline: 1.3694x; 1.1192x over previous
//
#include <hip/hip_runtime.h>
#include <cstddef>
#include <cstdint>

// ---------------------------------------------------------------------------
// attention_net_noc: pointer-network decode step.
// R3: packed-fp32 rework. R2 counters: k_emb_g1 VALUBusy 81% -> VALU-issue
// bound. gfx950 has v_pk_fma_f32 (2x fp32 FMA per issue slot, bit-identical
// to scalar). Process the 2 rows/thread as float2 ext-vectors via
// __builtin_elementwise_fma -> llvm.fma.v2f32 -> v_pk_fma_f32. Also hoist the
// per-thread qk prologue of k_emb_g1 into a tiny k_init kernel.
// ---------------------------------------------------------------------------

constexpr int NJ = 1000000;
constexpr int NM = 500000;
constexpr float NEGV = -1e8f;

constexpr int BLK = 256;
constexpr int ROWS_PER_BLK = 512;            // 2 rows per thread
constexpr int GB_J2 = (NJ + ROWS_PER_BLK - 1) / ROWS_PER_BLK;  // 1954
constexpr int GB_M2 = (NM + ROWS_PER_BLK - 1) / ROWS_PER_BLK;  // 977
constexpr int GB_TOT2 = GB_J2 + GB_M2;                          // 2931

// ---- workspace layout (float offsets from start of d_ws) ----
constexpr int S_QKJA = 0;    // 16: ja_Wq@g1 + ja_bq
constexpr int S_QK2J = 16;   // 16: aj_Wq@e_js + aj_bq
constexpr int S_QK2M = 32;   // 16: am_Wq@e_js + am_bq
constexpr int S_EJS  = 48;   // 16: E_j[sel_j]
constexpr int S_QKMA = 64;   // 16: ma_Wq@g2 + ma_bq
constexpr int S_LOGPJ = 80;
constexpr int S_SELJ  = 81;  // stored as float (exact, < 2^24)
constexpr int S_QK1J  = 96;  // 16: aj_Wq@last_j + aj_bq   (k_init)
constexpr int S_QK1M  = 112; // 16: am_Wq@last_j + am_bq   (k_init)
constexpr int P1J = 128;                       // GB_J2*17 glimpse partials (l, s[16])
constexpr int P1M = P1J + GB_J2 * 17;          // GB_M2*17
constexpr int P2V = P1M + GB_M2 * 17;          // GB_J2 argmax vals (mlogits reuses)
constexpr int P2I = P2V + GB_J2;
constexpr int P2L = P2I + GB_J2;
constexpr size_t E_OFF = 65536;                // float offset of E_j cache
static_assert(P2L + GB_J2 <= (int)E_OFF, "partials overflow into E cache");

typedef float v2f __attribute__((ext_vector_type(2)));

struct Params {
    const float *jobs, *machines;
    const int *mask;
    const float *jW1, *jb1, *jW2, *jb2;
    const float *mW1, *mb1, *mW2, *mb2;
    const float *aj_Wq, *aj_bq, *aj_Wr, *aj_V;
    const float *am_Wq, *am_bq, *am_Wr, *am_V;
    const float *ja_Wq, *ja_bq, *ja_Wr, *ja_V;
    const float *ma_Wq, *ma_bq, *ma_Wr, *ma_V;
    const float *g1W, *g1b, *g2W, *g2b, *last_j;
    float *S;        // smalls + partials (in ws)
    float *Ej, *Em;  // embedding cache (in ws; valid only if CACHE)
    float *out;
};

// ---------------------------------------------------------------------------
// device helpers
// ---------------------------------------------------------------------------

// tanh(x) = 1 - 2/(e^{2x}+1). |x| <= ~3 here; abs err ~2e-7 vs np.tanh.
__device__ __forceinline__ float fast_tanh(float x) {
    float e = __expf(2.0f * x);
    return 1.0f - __fdividef(2.0f, e + 1.0f);
}

__device__ __forceinline__ v2f vbc(float a) { v2f r; r.x = a; r.y = a; return r; }

// packed fma: one v_pk_fma_f32 issue slot for two fp32 FMAs (bit-identical)
__device__ __forceinline__ v2f vfma(float w, v2f b, v2f c) {
    return __builtin_elementwise_fma(vbc(w), b, c);
}
__device__ __forceinline__ v2f vfma2(v2f a, v2f b, v2f c) {
    return __builtin_elementwise_fma(a, b, c);
}
__device__ __forceinline__ v2f vtanh(v2f a) {
    v2f r; r.x = fast_tanh(a.x); r.y = fast_tanh(a.y); return r;
}

__device__ __forceinline__ void load16(const float* __restrict__ X, size_t r, float (&x)[16]) {
    const float4* p4 = reinterpret_cast<const float4*>(X) + r * 4;
    float4 a = p4[0], b = p4[1], c = p4[2], d = p4[3];
    x[0]=a.x; x[1]=a.y; x[2]=a.z; x[3]=a.w;
    x[4]=b.x; x[5]=b.y; x[6]=b.z; x[7]=b.w;
    x[8]=c.x; x[9]=c.y; x[10]=c.z; x[11]=c.w;
    x[12]=d.x; x[13]=d.y; x[14]=d.z; x[15]=d.w;
}

// load rows rA, rB and pack feature-wise into v2f lanes (.x=rowA, .y=rowB)
__device__ __forceinline__ void load16_v2(const float* __restrict__ X, size_t rA, size_t rB,
                                          v2f (&x)[16]) {
    float a[16], b[16];
    load16(X, rA, a);
    load16(X, rB, b);
#pragma unroll
    for (int k = 0; k < 16; ++k) { x[k].x = a[k]; x[k].y = b[k]; }
}

__device__ __forceinline__ void store16_lane(float* __restrict__ X, size_t r,
                                             const v2f (&x)[16], int lane) {
    float4* p4 = reinterpret_cast<float4*>(X) + r * 4;
    if (lane == 0) {
        p4[0] = make_float4(x[0].x, x[1].x, x[2].x, x[3].x);
        p4[1] = make_float4(x[4].x, x[5].x, x[6].x, x[7].x);
        p4[2] = make_float4(x[8].x, x[9].x, x[10].x, x[11].x);
        p4[3] = make_float4(x[12].x, x[13].x, x[14].x, x[15].x);
    } else {
        p4[0] = make_float4(x[0].y, x[1].y, x[2].y, x[3].y);
        p4[1] = make_float4(x[4].y, x[5].y, x[6].y, x[7].y);
        p4[2] = make_float4(x[8].y, x[9].y, x[10].y, x[11].y);
        p4[3] = make_float4(x[12].y, x[13].y, x[14].y, x[15].y);
    }
}

// e = tanh(W2 @ tanh(W1 @ x + b1) + b2) for a packed row-pair
__device__ __forceinline__ void emb16_v2(const v2f (&x)[16],
                                         const float* __restrict__ W1, const float* __restrict__ b1,
                                         const float* __restrict__ W2, const float* __restrict__ b2,
                                         v2f (&e)[16]) {
    v2f h[16];
#pragma unroll
    for (int i = 0; i < 16; ++i) {
        v2f a = vbc(b1[i]);
#pragma unroll
        for (int k = 0; k < 16; ++k) a = vfma(W1[i * 16 + k], x[k], a);
        h[i] = vtanh(a);
    }
#pragma unroll
    for (int i = 0; i < 16; ++i) {
        v2f a = vbc(b2[i]);
#pragma unroll
        for (int k = 0; k < 16; ++k) a = vfma(W2[i * 16 + k], h[k], a);
        e[i] = vtanh(a);
    }
}

// logit = tanh(qk + Wr @ e) . V for a packed row-pair
__device__ __forceinline__ v2f att_logit_v2(const v2f (&e)[16], const float (&qk)[16],
                                            const float* __restrict__ Wr,
                                            const float* __restrict__ V) {
    v2f acc = vbc(0.0f);
#pragma unroll
    for (int i = 0; i < 16; ++i) {
        v2f r = vbc(qk[i]);
#pragma unroll
        for (int k = 0; k < 16; ++k) r = vfma(Wr[i * 16 + k], e[k], r);
        acc = vfma2(vbc(V[i]), vtanh(r), acc);
    }
    return acc;
}

__device__ __forceinline__ float wave_reduce_sum(float v) {
#pragma unroll
    for (int off = 32; off > 0; off >>= 1) v += __shfl_xor(v, off, 64);
    return v;
}

__device__ __forceinline__ void wave_reduce_argmax(float &v, int &idx) {
#pragma unroll
    for (int off = 32; off > 0; off >>= 1) {
        float ov = __shfl_xor(v, off, 64);
        int oi = __shfl_xor(idx, off, 64);
        if (ov > v || (ov == v && oi < idx)) { v = ov; idx = oi; }
    }
}

__device__ __forceinline__ float block_sum(float v) {
    __shared__ float sm[4];
    v = wave_reduce_sum(v);
    __syncthreads();
    if ((threadIdx.x & 63) == 0) sm[threadIdx.x >> 6] = v;
    __syncthreads();
    return sm[0] + sm[1] + sm[2] + sm[3];
}

__device__ __forceinline__ void block_argmax(float &v, int &i) {
    __shared__ float sv[4];
    __shared__ int si[4];
    wave_reduce_argmax(v, i);
    __syncthreads();
    if ((threadIdx.x & 63) == 0) { sv[threadIdx.x >> 6] = v; si[threadIdx.x >> 6] = i; }
    __syncthreads();
    float bv = sv[0]; int bi = si[0];
#pragma unroll
    for (int k = 1; k < 4; ++k)
        if (sv[k] > bv || (sv[k] == bv && si[k] < bi)) { bv = sv[k]; bi = si[k]; }
    v = bv; i = bi;
}

// reduce (l, s[16]) across the block, write 17 floats to dst
__device__ __forceinline__ void block_sum17(float l, float (&s)[16], float* dst) {
    l = wave_reduce_sum(l);
#pragma unroll
    for (int i = 0; i < 16; ++i) s[i] = wave_reduce_sum(s[i]);
    __shared__ float red[4][17];
    int w = threadIdx.x >> 6, ln = threadIdx.x & 63;
    if (ln == 0) {
        red[w][0] = l;
#pragma unroll
        for (int i = 0; i < 16; ++i) red[w][1 + i] = s[i];
    }
    __syncthreads();
    if (threadIdx.x < 17)
        dst[threadIdx.x] = red[0][threadIdx.x] + red[1][threadIdx.x] + red[2][threadIdx.x] + red[3][threadIdx.x];
}

// ---------------------------------------------------------------------------
// K0: precompute phase-1 query vectors qk1j/qk1m (removes 256-FMA prologue
// from every k_emb_g1 thread).
// ---------------------------------------------------------------------------
__global__ __launch_bounds__(64) void k_init(Params p) {
    if (threadIdx.x < 32) {
        const bool isJ = threadIdx.x < 16;
        const int i = threadIdx.x & 15;
        const float* Wq = isJ ? p.aj_Wq : p.am_Wq;
        const float* bq = isJ ? p.aj_bq : p.am_bq;
        float a = bq[i];
#pragma unroll
        for (int k = 0; k < 16; ++k) a = fmaf(Wq[i * 16 + k], p.last_j[k], a);
        p.S[(isJ ? S_QK1J : S_QK1M) + i] = a;
    }
}

// ---------------------------------------------------------------------------
// K1: embeddings (optionally cached to ws) + glimpse-1 partial sums.
// blocks [0,GB_J2) -> jobs, [GB_J2,GB_TOT2) -> machines. 2 rows/thread.
// ---------------------------------------------------------------------------
template <bool CACHE>
__global__ __launch_bounds__(BLK) void k_emb_g1(Params p) {
    const bool isJob = blockIdx.x < GB_J2;
    const float* X  = isJob ? p.jobs : p.machines;
    const float* W1 = isJob ? p.jW1 : p.mW1;
    const float* b1 = isJob ? p.jb1 : p.mb1;
    const float* W2 = isJob ? p.jW2 : p.mW2;
    const float* b2 = isJob ? p.jb2 : p.mb2;
    const float* Wr = isJob ? p.aj_Wr : p.am_Wr;
    const float* V  = isJob ? p.aj_V  : p.am_V;
    float* E = isJob ? p.Ej : p.Em;
    const int n  = isJob ? NJ : NM;
    const int b0 = isJob ? (int)blockIdx.x : (int)blockIdx.x - GB_J2;

    float qk[16];
    {
        const float* src = p.S + (isJob ? S_QK1J : S_QK1M);
#pragma unroll
        for (int i = 0; i < 16; ++i) qk[i] = src[i];
    }

    const int r0 = b0 * ROWS_PER_BLK + (int)threadIdx.x;
    const int r1 = r0 + BLK;
    const bool v0 = r0 < n, v1 = r1 < n;
    const size_t a0 = (size_t)(v0 ? r0 : 0);
    const size_t a1 = (size_t)(v1 ? r1 : 0);

    v2f x[16], e[16];
    load16_v2(X, a0, a1, x);
    emb16_v2(x, W1, b1, W2, b2, e);
    if (CACHE) {
        if (v0) store16_lane(E, a0, e, 0);
        if (v1) store16_lane(E, a1, e, 1);
    }
    v2f lg = att_logit_v2(e, qk, Wr, V);
    // |logit| <= sum|V| ~ 0.6 -> exp never overflows; no max-shift needed.
    float pw0 = v0 ? __expf(lg.x) : 0.0f;
    float pw1 = v1 ? __expf(lg.y) : 0.0f;
    float l = pw0 + pw1, s[16];
#pragma unroll
    for (int i = 0; i < 16; ++i) s[i] = fmaf(pw0, e[i].x, pw1 * e[i].y);

    block_sum17(l, s, p.S + (isJob ? P1J : P1M) + (size_t)b0 * 17);
}

// ---------------------------------------------------------------------------
// Combine partials -> g (g1 or g2) -> next-stage qk vector. Single block.
// ---------------------------------------------------------------------------
__global__ __launch_bounds__(BLK) void k_combine_g(Params p, int phase) {
    const float* PJ = p.S + P1J;
    const float* PM = p.S + P1M;
    float accJ[17], accM[17];
#pragma unroll
    for (int c = 0; c < 17; ++c) { accJ[c] = 0.0f; accM[c] = 0.0f; }
    for (int i = threadIdx.x; i < GB_J2; i += BLK)
#pragma unroll
        for (int c = 0; c < 17; ++c) accJ[c] += PJ[i * 17 + c];
    for (int i = threadIdx.x; i < GB_M2; i += BLK)
#pragma unroll
        for (int c = 0; c < 17; ++c) accM[c] += PM[i * 17 + c];

    __shared__ float totJ[17], totM[17];
    for (int c = 0; c < 17; ++c) {
        float t = block_sum(accJ[c]);
        if (threadIdx.x == 0) totJ[c] = t;
        t = block_sum(accM[c]);
        if (threadIdx.x == 0) totM[c] = t;
    }
    __syncthreads();

    __shared__ float cb[48], gbuf[16];
    if (threadIdx.x < 16) {
        int i = threadIdx.x;
        cb[i]      = phase ? p.S[S_EJS + i] : p.last_j[i];
        cb[16 + i] = totJ[1 + i] / totJ[0];   // softmax-weighted sum / partition
        cb[32 + i] = totM[1 + i] / totM[0];
    }
    __syncthreads();
    const float* gW  = phase ? p.g2W : p.g1W;
    const float* gbv = phase ? p.g2b : p.g1b;
    if (threadIdx.x < 16) {
        int i = threadIdx.x;
        float a = gbv[i];
#pragma unroll
        for (int k = 0; k < 48; ++k) a = fmaf(gW[i * 48 + k], cb[k], a);
        gbuf[i] = fast_tanh(a);
    }
    __syncthreads();
    const float* Wq = phase ? p.ma_Wq : p.ja_Wq;
    const float* bq = phase ? p.ma_bq : p.ja_bq;
    const int off = phase ? S_QKMA : S_QKJA;
    if (threadIdx.x < 16) {
        int i = threadIdx.x;
        float a = bq[i];
#pragma unroll
        for (int k = 0; k < 16; ++k) a = fmaf(Wq[i * 16 + k], gbuf[k], a);
        p.S[off + i] = a;
    }
}

// ---------------------------------------------------------------------------
// K3: job pointer logits -> masked argmax + sum-exp partials. 2 rows/thread.
// ---------------------------------------------------------------------------
template <bool CACHE>
__global__ __launch_bounds__(BLK) void k_jlogits(Params p) {
    float qk[16];
#pragma unroll
    for (int i = 0; i < 16; ++i) qk[i] = p.S[S_QKJA + i];

    const int r0 = blockIdx.x * ROWS_PER_BLK + (int)threadIdx.x;
    const int r1 = r0 + BLK;
    const bool v0 = r0 < NJ, v1 = r1 < NJ;
    const size_t a0 = (size_t)(v0 ? r0 : 0);
    const size_t a1 = (size_t)(v1 ? r1 : 0);

    v2f e[16];
    if (CACHE) {
        load16_v2(p.Ej, a0, a1, e);
    } else {
        v2f x[16];
        load16_v2(p.jobs, a0, a1, x);
        emb16_v2(x, p.jW1, p.jb1, p.jW2, p.jb2, e);
    }
    v2f lg = att_logit_v2(e, qk, p.ja_Wr, p.ja_V);
    const bool m0 = v0 && (p.mask[a0] != 0);
    const bool m1 = v1 && (p.mask[a1] != 0);
    float l = (m0 ? __expf(lg.x) : 0.0f) + (m1 ? __expf(lg.y) : 0.0f);
    float am0 = m0 ? lg.x : NEGV - 1.0f;   // invalid rows below masked NEG
    float am1 = m1 ? lg.y : NEGV - 1.0f;
    float best;
    int bi;
    if (am0 >= am1) { best = am0; bi = r0; }
    else            { best = am1; bi = r1; }

    l = wave_reduce_sum(l);
    wave_reduce_argmax(best, bi);
    __shared__ float rl[4], rv[4];
    __shared__ int ri[4];
    int w = threadIdx.x >> 6, ln = threadIdx.x & 63;
    if (ln == 0) { rl[w] = l; rv[w] = best; ri[w] = bi; }
    __syncthreads();
    if (threadIdx.x == 0) {
        float L = rl[0] + rl[1] + rl[2] + rl[3];
        float v = rv[0]; int i = ri[0];
#pragma unroll
        for (int k = 1; k < 4; ++k)
            if (rv[k] > v || (rv[k] == v && ri[k] < i)) { v = rv[k]; i = ri[k]; }
        p.S[P2V + blockIdx.x] = v;
        p.S[P2I + blockIdx.x] = (float)i;   // exact: i < 2^24
        p.S[P2L + blockIdx.x] = L;
    }
}

// ---------------------------------------------------------------------------
// C2: global argmax over job logits; logp_j; e_js = emb(jobs[sel_j]); qk2j/qk2m
// ---------------------------------------------------------------------------
__global__ __launch_bounds__(BLK) void k_combine2(Params p) {
    float v = -3.4e38f; int vi = 0x7fffffff; float l = 0.0f;
    for (int i = threadIdx.x; i < GB_J2; i += BLK) {
        float pv = p.S[P2V + i];
        int pi = (int)p.S[P2I + i];
        if (pv > v || (pv == v && pi < vi)) { v = pv; vi = pi; }
        l += p.S[P2L + i];
    }
    l = block_sum(l);
    block_argmax(v, vi);
    const int sel = vi;

    __shared__ float xb[16], hb[16], eb[16];
    if (threadIdx.x < 16) xb[threadIdx.x] = p.jobs[(size_t)sel * 16 + threadIdx.x];
    __syncthreads();
    if (threadIdx.x < 16) {
        int i = threadIdx.x;
        float a = p.jb1[i];
#pragma unroll
        for (int k = 0; k < 16; ++k) a = fmaf(p.jW1[i * 16 + k], xb[k], a);
        hb[i] = fast_tanh(a);
    }
    __syncthreads();
    if (threadIdx.x < 16) {
        int i = threadIdx.x;
        float a = p.jb2[i];
#pragma unroll
        for (int k = 0; k < 16; ++k) a = fmaf(p.jW2[i * 16 + k], hb[k], a);
        float e = fast_tanh(a);
        eb[i] = e;
        p.S[S_EJS + i] = e;
    }
    __syncthreads();
    if (threadIdx.x < 16) {
        int i = threadIdx.x;
        float a1 = p.aj_bq[i], a2 = p.am_bq[i];
#pragma unroll
        for (int k = 0; k < 16; ++k) {
            a1 = fmaf(p.aj_Wq[i * 16 + k], eb[k], a1);
            a2 = fmaf(p.am_Wq[i * 16 + k], eb[k], a2);
        }
        p.S[S_QK2J + i] = a1;
        p.S[S_QK2M + i] = a2;
    }
    if (threadIdx.x == 0) {
        p.S[S_LOGPJ] = v - logf(l);     // log_softmax at the argmax
        p.S[S_SELJ] = (float)sel;
    }
}

// ---------------------------------------------------------------------------
// K4: glimpse-2 over jobs (aj_*) and machines (am_*), query e_js. 2 rows/thread.
// Writes partials into the (already consumed) P1 buffers.
// ---------------------------------------------------------------------------
template <bool CACHE>
__global__ __launch_bounds__(BLK) void k_glimpse2(Params p) {
    const bool isJob = blockIdx.x < GB_J2;
    const float* Wr = isJob ? p.aj_Wr : p.am_Wr;
    const float* V  = isJob ? p.aj_V  : p.am_V;
    const float* E  = isJob ? p.Ej : p.Em;
    const float* X  = isJob ? p.jobs : p.machines;
    const float* W1 = isJob ? p.jW1 : p.mW1;
    const float* b1 = isJob ? p.jb1 : p.mb1;
    const float* W2 = isJob ? p.jW2 : p.mW2;
    const float* b2 = isJob ? p.jb2 : p.mb2;
    const int n  = isJob ? NJ : NM;
    const int b0 = isJob ? (int)blockIdx.x : (int)blockIdx.x - GB_J2;
    const int qoff = isJob ? S_QK2J : S_QK2M;

    float qk[16];
#pragma unroll
    for (int i = 0; i < 16; ++i) qk[i] = p.S[qoff + i];

    const int r0 = b0 * ROWS_PER_BLK + (int)threadIdx.x;
    const int r1 = r0 + BLK;
    const bool v0 = r0 < n, v1 = r1 < n;
    const size_t a0 = (size_t)(v0 ? r0 : 0);
    const size_t a1 = (size_t)(v1 ? r1 : 0);

    v2f e[16];
    if (CACHE) {
        load16_v2(E, a0, a1, e);
    } else {
        v2f x[16];
        load16_v2(X, a0, a1, x);
        emb16_v2(x, W1, b1, W2, b2, e);
    }
    v2f lg = att_logit_v2(e, qk, Wr, V);
    float pw0 = v0 ? __expf(lg.x) : 0.0f;
    float pw1 = v1 ? __expf(lg.y) : 0.0f;
    float l = pw0 + pw1, s[16];
#pragma unroll
    for (int i = 0; i < 16; ++i) s[i] = fmaf(pw0, e[i].x, pw1 * e[i].y);

    block_sum17(l, s, p.S + (isJob ? P1J : P1M) + (size_t)b0 * 17);
}

// ---------------------------------------------------------------------------
// K5: machine logits -> argmax + sum-exp partials. 2 rows/thread.
// Writes into the (already consumed) P2 buffers.
// ---------------------------------------------------------------------------
template <bool CACHE>
__global__ __launch_bounds__(BLK) void k_mlogits(Params p) {
    float qk[16];
#pragma unroll
    for (int i = 0; i < 16; ++i) qk[i] = p.S[S_QKMA + i];

    const int r0 = blockIdx.x * ROWS_PER_BLK + (int)threadIdx.x;
    const int r1 = r0 + BLK;
    const bool v0 = r0 < NM, v1 = r1 < NM;
    const size_t a0 = (size_t)(v0 ? r0 : 0);
    const size_t a1 = (size_t)(v1 ? r1 : 0);

    v2f e[16];
    if (CACHE) {
        load16_v2(p.Em, a0, a1, e);
    } else {
        v2f x[16];
        load16_v2(p.machines, a0, a1, x);
        emb16_v2(x, p.mW1, p.mb1, p.mW2, p.mb2, e);
    }
    v2f lg = att_logit_v2(e, qk, p.ma_Wr, p.ma_V);
    float l = (v0 ? __expf(lg.x) : 0.0f) + (v1 ? __expf(lg.y) : 0.0f);
    float am0 = v0 ? lg.x : -3.4e38f;
    float am1 = v1 ? lg.y : -3.4e38f;
    float best;
    int bi;
    if (am0 >= am1) { best = am0; bi = r0; }
    else            { best = am1; bi = r1; }

    l = wave_reduce_sum(l);
    wave_reduce_argmax(best, bi);
    __shared__ float rl[4], rv[4];
    __shared__ int ri[4];
    int w = threadIdx.x >> 6, ln = threadIdx.x & 63;
    if (ln == 0) { rl[w] = l; rv[w] = best; ri[w] = bi; }
    __syncthreads();
    if (threadIdx.x == 0) {
        float L = rl[0] + rl[1] + rl[2] + rl[3];
        float v = rv[0]; int i = ri[0];
#pragma unroll
        for (int k = 1; k < 4; ++k)
            if (rv[k] > v || (rv[k] == v && ri[k] < i)) { v = rv[k]; i = ri[k]; }
        p.S[P2V + blockIdx.x] = v;
        p.S[P2I + blockIdx.x] = (float)i;
        p.S[P2L + blockIdx.x] = L;
    }
}

// ---------------------------------------------------------------------------
// C4: final combine -> outputs [sel_j, sel_m, logpas] as float32
// ---------------------------------------------------------------------------
__global__ __launch_bounds__(BLK) void k_combine4(Params p) {
    float v = -3.4e38f; int vi = 0x7fffffff; float l = 0.0f;
    for (int i = threadIdx.x; i < GB_M2; i += BLK) {
        float pv = p.S[P2V + i];
        int pi = (int)p.S[P2I + i];
        if (pv > v || (pv == v && pi < vi)) { v = pv; vi = pi; }
        l += p.S[P2L + i];
    }
    l = block_sum(l);
    block_argmax(v, vi);
    if (threadIdx.x == 0) {
        p.out[0] = p.S[S_SELJ];
        p.out[1] = (float)vi;
        p.out[2] = p.S[S_LOGPJ] + (v - logf(l));
    }
}

// ---------------------------------------------------------------------------
extern "C" void kernel_launch(void* const* d_in, const int* in_sizes, int n_in,
                              void* d_out, int out_size, void* d_ws, size_t ws_size,
                              hipStream_t stream) {
    Params p;
    p.jobs     = (const float*)d_in[0];
    p.machines = (const float*)d_in[1];
    p.mask     = (const int*)d_in[2];
    p.jW1 = (const float*)d_in[3];  p.jb1 = (const float*)d_in[4];
    p.jW2 = (const float*)d_in[5];  p.jb2 = (const float*)d_in[6];
    p.mW1 = (const float*)d_in[7];  p.mb1 = (const float*)d_in[8];
    p.mW2 = (const float*)d_in[9];  p.mb2 = (const float*)d_in[10];
    p.aj_Wq = (const float*)d_in[11]; p.aj_bq = (const float*)d_in[12];
    p.aj_Wr = (const float*)d_in[13]; p.aj_V  = (const float*)d_in[14];
    p.am_Wq = (const float*)d_in[15]; p.am_bq = (const float*)d_in[16];
    p.am_Wr = (const float*)d_in[17]; p.am_V  = (const float*)d_in[18];
    p.ja_Wq = (const float*)d_in[19]; p.ja_bq = (const float*)d_in[20];
    p.ja_Wr = (const float*)d_in[21]; p.ja_V  = (const float*)d_in[22];
    p.ma_Wq = (const float*)d_in[23]; p.ma_bq = (const float*)d_in[24];
    p.ma_Wr = (const float*)d_in[25]; p.ma_V  = (const float*)d_in[26];
    p.g1W = (const float*)d_in[27]; p.g1b = (const float*)d_in[28];
    p.g2W = (const float*)d_in[29]; p.g2b = (const float*)d_in[30];
    p.last_j = (const float*)d_in[31];
    p.S = (float*)d_ws;
    p.Ej = (float*)d_ws + E_OFF;
    p.Em = p.Ej + (size_t)NJ * 16;
    p.out = (float*)d_out;

    const size_t needed = (E_OFF + (size_t)(NJ + NM) * 16) * sizeof(float);
    const bool cache = ws_size >= needed;

    k_init<<<1, 64, 0, stream>>>(p);
    if (cache) {
        k_emb_g1<true><<<GB_TOT2, BLK, 0, stream>>>(p);
        k_combine_g<<<1, BLK, 0, stream>>>(p, 0);
        k_jlogits<true><<<GB_J2, BLK, 0, stream>>>(p);
        k_combine2<<<1, BLK, 0, stream>>>(p);
        k_glimpse2<true><<<GB_TOT2, BLK, 0, stream>>>(p);
        k_combine_g<<<1, BLK, 0, stream>>>(p, 1);
        k_mlogits<true><<<GB_M2, BLK, 0, stream>>>(p);
        k_combine4<<<1, BLK, 0, stream>>>(p);
    } else {
        k_emb_g1<false><<<GB_TOT2, BLK, 0, stream>>>(p);
        k_combine_g<<<1, BLK, 0, stream>>>(p, 0);
        k_jlogits<false><<<GB_J2, BLK, 0, stream>>>(p);
        k_combine2<<<1, BLK, 0, stream>>>(p);
        k_glimpse2<false><<<GB_TOT2, BLK, 0, stream>>>(p);
        k_combine_g<<<1, BLK, 0, stream>>>(p, 1);
        k_mlogits<false><<<GB_M2, BLK, 0, stream>>>(p);
        k_combine4<<<1, BLK, 0, stream>>>(p);
    }
}